// Round 11
// baseline (453.034 us; speedup 1.0000x reference)
//
#include <hip/hip_runtime.h>
#include <hip/hip_bf16.h>
#include <stdint.h>

#define S_LEN 2048
#define HDIM  2048
#define NH    16
#define HD    128
#define BATCH 4

typedef __attribute__((ext_vector_type(8))) short bf16x8;
typedef __attribute__((ext_vector_type(4))) float f32x4;
typedef __attribute__((ext_vector_type(4))) float float4v;
typedef __attribute__((ext_vector_type(4))) unsigned short u16x4;

__device__ __forceinline__ void gload_lds16(const void* g, void* l) {
  __builtin_amdgcn_global_load_lds(
      (const __attribute__((address_space(1))) unsigned int*)g,
      (__attribute__((address_space(3))) unsigned int*)l,
      16, 0, 0);
}

__device__ __forceinline__ unsigned short f2bf(float x) {
  __hip_bfloat16 b = __float2bfloat16(x);
  return *reinterpret_cast<unsigned short*>(&b);
}

#define SL2E 0.1275174465f   // (1/sqrt(128)) * log2(e) — folded into Q projection

// ---------------- fp32 -> bf16 convert: X + 4 weights in ONE launch ----------------
__global__ __launch_bounds__(256) void cvt5_kernel(
    const float* __restrict__ x,
    const float* __restrict__ w0, const float* __restrict__ w1,
    const float* __restrict__ w2, const float* __restrict__ w3,
    unsigned short* __restrict__ ox,
    unsigned short* __restrict__ o0, unsigned short* __restrict__ o1,
    unsigned short* __restrict__ o2, unsigned short* __restrict__ o3,
    int n4x, int n4w) {
  const int y = blockIdx.y;
  const float* in = (y == 0) ? x : (y == 1) ? w0 : (y == 2) ? w1 : (y == 3) ? w2 : w3;
  unsigned short* out = (y == 0) ? ox : (y == 1) ? o0 : (y == 2) ? o1 : (y == 3) ? o2 : o3;
  const int n4 = (y == 0) ? n4x : n4w;
  int stride = gridDim.x * blockDim.x;
  for (int i = blockIdx.x * blockDim.x + threadIdx.x; i < n4; i += stride) {
    float4v v = *(const float4v*)(in + (size_t)i * 4);
    u16x4 o;
    o.x = f2bf(v.x); o.y = f2bf(v.y); o.z = f2bf(v.z); o.w = f2bf(v.w);
    *(u16x4*)(out + (size_t)i * 4) = o;
  }
}

// ============ GEMM 256x256 8-phase (T2+T3+T4+T5): C = (A * B^T + bias)*scale ======
// 512 thr = 8 waves (2M x 4N), per-wave 128x64 out, BK=64, 2 K-tiles/iter.
// LDS 128KB: buf0 {A 32K | B 32K} buf1 {A 32K | B 32K}; tiles [256 rows][64 k],
// 16B-chunk swizzle c ^= row&7 (inverse-swizzled global src + swizzled ds_read).
// gload source offset uses the FULL 64-lane index (HW writes dest+lane*16):
// row = lane>>3, chunk = (lane&7)^(lane>>3)  [r7 bug: used lane&15 -> absmax 4.28].
// Sync skeleton = verified m201 template: per phase
//   {ds_reads | stage 1 half} bar ; lgkmcnt(0) ; MFMA ; bar
// Stage map: ph0:A0(v) ph1:A1(v) ph2:B0(u+2) ph3:B1(u+2)+vmcnt(4)
//            ph4:A0(u+2) ph5:A1(u+2) ph6:B0(v+2) ph7:B1(v+2)+vmcnt(4)
// Epilogue stages clamp the K-tile index; vmcnt(0) drains before exit.
// OUTMODE: 0 = bf16 row-major C, 1 = f32 row-major C,
//          2 = bf16 scattered to Vt[b,h,d,s] (fused V transpose).

#define G8_VMW(N) asm volatile("s_waitcnt vmcnt(" #N ")" ::: "memory")
#define G8_BAR1() do { __builtin_amdgcn_sched_barrier(0); __builtin_amdgcn_s_barrier(); \
  asm volatile("s_waitcnt lgkmcnt(0)" ::: "memory"); __builtin_amdgcn_sched_barrier(0); } while (0)
#define G8_BAR2() do { __builtin_amdgcn_sched_barrier(0); __builtin_amdgcn_s_barrier(); \
  __builtin_amdgcn_sched_barrier(0); } while (0)

#define G8_STAGE(ISB, BUF, HALF, KT) do {                                          \
  int kt_ = (KT); if (kt_ > nkt1) kt_ = nkt1;                                      \
  const char* gs_ = ((ISB) ? Bg : Ag) +                                            \
      (size_t)(((ISB) ? bn : bm) * 256 + (HALF) * 128 + w * 16) * (size_t)K2 +     \
      (size_t)kt_ * 128;                                                           \
  char* ld_ = lds + (BUF) * 65536 + (ISB) * 32768 + ((HALF) * 128 + w * 16) * 128; \
  gload_lds16(gs_ + sLn, ld_);                                                     \
  gload_lds16(gs_ + 8 * (size_t)K2 + sLn, ld_ + 1024);                             \
} while (0)

#define G8_RDA(BUF, MI0) do {                                                      \
  _Pragma("unroll") for (int mi = 0; mi < 4; ++mi)                                 \
  _Pragma("unroll") for (int kk = 0; kk < 2; ++kk)                                 \
    a[mi][kk] = *(const bf16x8*)(lds + (BUF) * 65536 +                             \
        (wm + ((MI0) + mi) * 16 + ln) * 128 + ((((kk << 2) + g) ^ ln7) << 4));     \
} while (0)

#define G8_RDB(BUF, NI0, BREG) do {                                                \
  _Pragma("unroll") for (int ni = 0; ni < 2; ++ni)                                 \
  _Pragma("unroll") for (int kk = 0; kk < 2; ++kk)                                 \
    BREG[ni][kk] = *(const bf16x8*)(lds + (BUF) * 65536 + 32768 +                  \
        (wn + ((NI0) + ni) * 16 + ln) * 128 + ((((kk << 2) + g) ^ ln7) << 4));     \
} while (0)

#define G8_MFMA(M0, N0, BREG) do {                                                 \
  __builtin_amdgcn_s_setprio(1);                                                   \
  _Pragma("unroll") for (int mi = 0; mi < 4; ++mi)                                 \
  _Pragma("unroll") for (int ni = 0; ni < 2; ++ni)                                 \
  _Pragma("unroll") for (int kk = 0; kk < 2; ++kk)                                 \
    acc[(M0) + mi][(N0) + ni] = __builtin_amdgcn_mfma_f32_16x16x32_bf16(           \
        a[mi][kk], BREG[ni][kk], acc[(M0) + mi][(N0) + ni], 0, 0, 0);              \
  __builtin_amdgcn_s_setprio(0);                                                   \
} while (0)

template<int OUTMODE>
__global__ __launch_bounds__(512, 2) void gemm8(
    const __hip_bfloat16* __restrict__ A, const __hip_bfloat16* __restrict__ B,
    const float* __restrict__ bias, void* __restrict__ C,
    int M, int N, int K, float scale) {
  __shared__ char lds[131072];
  const int tid = threadIdx.x;
  const int w = tid >> 6;
  const int lane = tid & 63;
  const int g = lane >> 4;
  const int ln = lane & 15;
  const int ln7 = lane & 7;
  const int K2 = K * 2;
  const int nkt = K >> 6;        // K-tiles of 64
  const int nkt1 = nkt - 1;
  const int niter = nkt >> 1;

  // XCD-chunked bijective swizzle over nwg = (M/256)*(N/256), NBN = N/256
  const int NBN = N >> 8;
  const int nwg = (M >> 8) * NBN;
  const int cpx = nwg >> 3;      // nwg % 8 == 0 for our shapes
  const int bid = blockIdx.x;
  const int wg = (bid & 7) * cpx + (bid >> 3);
  const int bm = wg / NBN, bn = wg % NBN;

  const int wm = (w >> 2) * 128;  // wave row base within 256
  const int wn = (w & 3) * 64;    // wave col base within 256

  const char* Ag = (const char*)A;
  const char* Bg = (const char*)B;
  // per-lane gload source offset (FULL lane): row += lane>>3, chunk = (lane&7)^(lane>>3)
  const size_t sLn = (size_t)(lane >> 3) * (size_t)K2 +
                     (size_t)(((lane & 7) ^ (lane >> 3)) << 4);

  f32x4 acc[8][4];
#pragma unroll
  for (int mi = 0; mi < 8; ++mi)
#pragma unroll
    for (int ni = 0; ni < 4; ++ni) acc[mi][ni] = (f32x4){0.f, 0.f, 0.f, 0.f};

  // ---- prologue: A0(0) A1(0) B0(0) B1(0) B0(1) B1(1); wait tile0; barrier ----
  G8_STAGE(0, 0, 0, 0); G8_STAGE(0, 0, 1, 0);
  G8_STAGE(1, 0, 0, 0); G8_STAGE(1, 0, 1, 0);
  G8_STAGE(1, 1, 0, 1); G8_STAGE(1, 1, 1, 1);
  G8_VMW(4);
  G8_BAR2();

  for (int i = 0; i < niter; ++i) {
    const int v = 2 * i + 1, u2 = 2 * i + 2, v2 = 2 * i + 3;
    bf16x8 a[4][2], b0[2][2], b1[2][2];
    // ph0: tile u (buf0), quadrant m0-3 x n0-1
    G8_RDA(0, 0); G8_RDB(0, 0, b0);
    G8_STAGE(0, 1, 0, v);
    G8_BAR1();
    G8_MFMA(0, 0, b0);
    G8_BAR2();
    // ph1: m0-3 x n2-3
    G8_RDB(0, 2, b1);
    G8_STAGE(0, 1, 1, v);
    G8_BAR1();
    G8_MFMA(0, 2, b1);
    G8_BAR2();
    // ph2: m4-7 x n0-1
    G8_RDA(0, 4);
    G8_STAGE(1, 0, 0, u2);
    G8_BAR1();
    G8_MFMA(4, 0, b0);
    G8_BAR2();
    // ph3: m4-7 x n2-3   (+vmcnt(4): tile v fully landed for all waves after bar)
    G8_STAGE(1, 0, 1, u2);
    G8_VMW(4);
    G8_BAR1();
    G8_MFMA(4, 2, b1);
    G8_BAR2();
    // ph4: tile v (buf1), m0-3 x n0-1
    G8_RDA(1, 0); G8_RDB(1, 0, b0);
    G8_STAGE(0, 0, 0, u2);
    G8_BAR1();
    G8_MFMA(0, 0, b0);
    G8_BAR2();
    // ph5: m0-3 x n2-3
    G8_RDB(1, 2, b1);
    G8_STAGE(0, 0, 1, u2);
    G8_BAR1();
    G8_MFMA(0, 2, b1);
    G8_BAR2();
    // ph6: m4-7 x n0-1
    G8_RDA(1, 4);
    G8_STAGE(1, 1, 0, v2);
    G8_BAR1();
    G8_MFMA(4, 0, b0);
    G8_BAR2();
    // ph7: m4-7 x n2-3   (+vmcnt(4): tile u2 fully landed after bar)
    G8_STAGE(1, 1, 1, v2);
    G8_VMW(4);
    G8_BAR1();
    G8_MFMA(4, 2, b1);
    G8_BAR2();
  }

  // ---- drain in-flight tail stages, then epilogue ----
  G8_VMW(0);
#pragma unroll
  for (int ni = 0; ni < 4; ++ni) {
    const int col = bn * 256 + wn + ni * 16 + ln;
    const float bv = bias[col];
#pragma unroll
    for (int mi = 0; mi < 8; ++mi) {
      const int row0 = bm * 256 + wm + mi * 16 + g * 4;
      if (OUTMODE == 2) {
        // Vt[((b*NH+h)*HD + d)*S_LEN + s], col = h*HD+d, 4 consecutive s per lane
        const int h = col >> 7, d = col & 127;
        const size_t base = ((size_t)((row0 >> 11) * NH + h) * HD + d) * S_LEN +
                            (row0 & (S_LEN - 1));
        u16x4 pk;
#pragma unroll
        for (int r = 0; r < 4; ++r)
          pk[r] = f2bf((acc[mi][ni][r] + bv) * scale);
        *(u16x4*)((unsigned short*)C + base) = pk;
      } else {
#pragma unroll
        for (int r = 0; r < 4; ++r) {
          float val = (acc[mi][ni][r] + bv) * scale;
          if (OUTMODE == 1)
            ((float*)C)[(size_t)(row0 + r) * N + col] = val;
          else
            ((__hip_bfloat16*)C)[(size_t)(row0 + r) * N + col] = __float2bfloat16(val);
        }
      }
    }
  }
}

// ---------------- causal flash attention (gload_lds staged, 40 KB, 3 blocks/CU) ----
// 16 q-rows/wave (64/block) -> o[8]+qf[4]+sa[4] ~ 140 VGPR, fits (256,3)'s
// 170-reg budget (r3/r4 spill was at ~188 under the same cap).
// 32 q-tiles of 64 rows, weight qt+1, partitioned into 12 uniform-44 groups:
//   gy<10: {31-gy, 11+gy}; gy==10: {21,10,9,0}; gy==11: {8..1}
// (disjoint, complete, each sums 44). Grid (64,12) = 768 = exactly 3/CU,
// uniform finish; bid%8 == bh%8 keeps the XCD/L2 alignment from r10
// (8 blocks sharing one bh's K/V on the same XCD; FETCH 302->86 MB).
// Q is PRE-SCALED by log2e/sqrt(d) in its projection (log2-domain scores).
// LDS map: K [0,16K) | V [16K,32K) | P [32K,40K) (2KB/wave); swizzle rule #21.
#define DEFER_THR 8.0f       // T13 (log2 domain): P bounded by 2^8

__global__ __launch_bounds__(256, 3) void attn_kernel(
    const __hip_bfloat16* __restrict__ Q, const __hip_bfloat16* __restrict__ Kg,
    const __hip_bfloat16* __restrict__ Vt, __hip_bfloat16* __restrict__ O) {
  __shared__ char lds[40960];
  const int tid = threadIdx.x;
  const int w = tid >> 6;
  const int lane = tid & 63;
  const int g = lane >> 4;
  const int ln = lane & 15;
  const int bh = blockIdx.x;            // XCD-aligned: bid%8 == bh%8
  const int gy = blockIdx.y;            // 0..11, uniform weight-44 group
  const int b = bh >> 4, h = bh & 15;

  const char* Qb = (const char*)Q + ((size_t)b * S_LEN * HDIM + h * HD) * 2;
  const char* Kb = (const char*)Kg + ((size_t)b * S_LEN * HDIM + h * HD) * 2;
  const char* Vb = (const char*)Vt + ((size_t)bh * HD * S_LEN) * 2;
  char* ldsK = lds;
  char* ldsV = lds + 16384;
  char* pw   = lds + 32768 + w * 2048;

  const int kr = lane >> 4;   // K: row within 4-row group
  const int kc = lane & 15;   // K: 16B chunk 0..15
  const int vr = lane >> 3;   // V: row within 8-row group (== row&7)
  const int vc = lane & 7;    // V: 16B chunk 0..7

  auto stage = [&](int kv0) {
#pragma unroll
    for (int i = 0; i < 4; i++) {
      int r = w * 16 + i * 4 + kr;  // K row 0..63
      gload_lds16(Kb + (size_t)(kv0 + r) * (HDIM * 2) + ((kc ^ (r & 7)) << 4),
                  ldsK + (w * 16 + i * 4) * 256);
    }
#pragma unroll
    for (int i = 0; i < 4; i++) {
      int r = w * 32 + i * 8 + vr;  // V row (d) 0..127; r&7 == vr
      gload_lds16(Vb + (size_t)r * (S_LEN * 2) + (size_t)kv0 * 2 + ((vc ^ vr) << 4),
                  ldsV + (w * 32 + i * 8) * 128);
    }
  };

  const int cnt = (gy < 10) ? 2 : (gy == 10) ? 4 : 8;
  for (int pass = 0; pass < cnt; pass++) {
    int qt;  // block-uniform, branchy scalar (no runtime-indexed array: rule #20)
    if (gy < 10)       qt = (pass == 0) ? (31 - gy) : (11 + gy);
    else if (gy == 10) qt = (pass == 0) ? 21 : (pass == 1) ? 10 : (pass == 2) ? 9 : 0;
    else               qt = 8 - pass;
    const int q0 = qt * 64 + w * 16;  // this wave's first q row

    const int nt = qt + 1;      // block-uniform kv tile count (causal)
    __syncthreads();            // protect prior pass's last-tile LDS reads
    stage(0);                   // issue tile-0 staging first...

    // ...then overlap Q-fragment loads with the staging gloads
    bf16x8 qf[4];
#pragma unroll
    for (int dc = 0; dc < 4; dc++)
      qf[dc] = *(const bf16x8*)(Qb + (size_t)(q0 + ln) * HDIM * 2 +
                                (dc * 32 + g * 8) * 2);

    f32x4 o[8];
#pragma unroll
    for (int ds = 0; ds < 8; ds++) o[ds] = (f32x4){0.f, 0.f, 0.f, 0.f};
    float mrun[4], lrun[4];
#pragma unroll
    for (int r = 0; r < 4; r++) { mrun[r] = -__builtin_inff(); lrun[r] = 0.f; }

    __syncthreads();

    for (int t = 0; t < nt; t++) {
      const int kv0 = t * 64;

      if (kv0 <= q0 + 15) {  // wave-uniform: skip fully-masked tiles
        f32x4 sa[4];
#pragma unroll
        for (int ks = 0; ks < 4; ks++) sa[ks] = (f32x4){0.f, 0.f, 0.f, 0.f};
#pragma unroll
        for (int dc = 0; dc < 4; dc++) {
          bf16x8 kf[4];
#pragma unroll
          for (int ks = 0; ks < 4; ks++)
            kf[ks] = *(const bf16x8*)(ldsK + (ks * 16 + ln) * 256 +
                                      (((dc * 4 + g) ^ (ln & 7)) << 4));
          __builtin_amdgcn_s_setprio(1);   // T5: favor MFMA burst
#pragma unroll
          for (int ks = 0; ks < 4; ks++)
            sa[ks] = __builtin_amdgcn_mfma_f32_16x16x32_bf16(qf[dc], kf[ks], sa[ks], 0, 0, 0);
          __builtin_amdgcn_s_setprio(0);
        }
        // scores already log2-domain (Q pre-scaled); apply causal mask only
        const bool needmask = (kv0 + 63) > q0;
        if (needmask) {
#pragma unroll
          for (int ks = 0; ks < 4; ks++)
#pragma unroll
            for (int r = 0; r < 4; r++)
              if ((kv0 + ks * 16 + ln) > (q0 + g * 4 + r))
                sa[ks][r] = -__builtin_inff();
        }
        float pmax[4];
#pragma unroll
        for (int r = 0; r < 4; r++) {
          float mx = fmaxf(fmaxf(sa[0][r], sa[1][r]), fmaxf(sa[2][r], sa[3][r]));
          mx = fmaxf(mx, __shfl_xor(mx, 1));
          mx = fmaxf(mx, __shfl_xor(mx, 2));
          mx = fmaxf(mx, __shfl_xor(mx, 4));
          mx = fmaxf(mx, __shfl_xor(mx, 8));
          pmax[r] = mx;
        }
        float dmin = 1e30f;
#pragma unroll
        for (int r = 0; r < 4; r++)
          dmin = fminf(dmin, mrun[r] + DEFER_THR - pmax[r]);
        if (!__all(dmin >= 0.0f)) {
          float alpha[4];
#pragma unroll
          for (int r = 0; r < 4; r++) {
            float mn = fmaxf(mrun[r], pmax[r]);
            alpha[r] = exp2f(mrun[r] - mn);
            mrun[r] = mn;
            lrun[r] *= alpha[r];
          }
#pragma unroll
          for (int ds = 0; ds < 8; ds++)
#pragma unroll
            for (int r = 0; r < 4; r++) o[ds][r] *= alpha[r];
        }
        float rsum[4];
#pragma unroll
        for (int r = 0; r < 4; r++) rsum[r] = 0.f;
#pragma unroll
        for (int ks = 0; ks < 4; ks++)
#pragma unroll
          for (int r = 0; r < 4; r++) {
            float p = exp2f(sa[ks][r] - mrun[r]);
            sa[ks][r] = p;
            rsum[r] += p;
          }
#pragma unroll
        for (int r = 0; r < 4; r++) {
          float rs = rsum[r];
          rs += __shfl_xor(rs, 1);
          rs += __shfl_xor(rs, 2);
          rs += __shfl_xor(rs, 4);
          rs += __shfl_xor(rs, 8);
          lrun[r] += rs;
        }
        // ---- P -> LDS (bf16, XOR swizzle: chunk ^= row&7), rows 0..15 ----
#pragma unroll
        for (int ks = 0; ks < 4; ks++)
#pragma unroll
          for (int r = 0; r < 4; r++) {
            int row = g * 4 + r;
            int key = ks * 16 + ln;
            *(__hip_bfloat16*)(pw + row * 128 + (((key >> 3) ^ (row & 7)) << 4) + (key & 7) * 2) =
                __float2bfloat16(sa[ks][r]);
          }
        // ---- O += P V ----
#pragma unroll
        for (int kk = 0; kk < 2; kk++) {
          bf16x8 pa = *(const bf16x8*)(pw + ln * 128 + (((kk * 4 + g) ^ (ln & 7)) << 4));
          __builtin_amdgcn_s_setprio(1);   // T5
#pragma unroll
          for (int ds = 0; ds < 8; ds++) {
            bf16x8 vf = *(const bf16x8*)(ldsV + (ds * 16 + ln) * 128 +
                                         (((kk * 4 + g) ^ (ln & 7)) << 4));
            o[ds] = __builtin_amdgcn_mfma_f32_16x16x32_bf16(pa, vf, o[ds], 0, 0, 0);
          }
          __builtin_amdgcn_s_setprio(0);
        }
      }

      if (t + 1 < nt) {
        __syncthreads();
        stage(kv0 + 64);
        __syncthreads();
      }
    }
    float inv[4];
#pragma unroll
    for (int r = 0; r < 4; r++) inv[r] = 1.0f / lrun[r];
    __hip_bfloat16* Ob = O + (size_t)b * S_LEN * HDIM + h * HD;
#pragma unroll
    for (int ds = 0; ds < 8; ds++)
#pragma unroll
      for (int r = 0; r < 4; r++)
        Ob[(size_t)(q0 + g * 4 + r) * HDIM + ds * 16 + ln] =
            __float2bfloat16(o[ds][r] * inv[r]);
  }
}

extern "C" void kernel_launch(void* const* d_in, const int* in_sizes, int n_in,
                              void* d_out, int out_size, void* d_ws, size_t ws_size,
                              hipStream_t stream) {
  const float* X  = (const float*)d_in[0];
  const float* Wq = (const float*)d_in[2];
  const float* bq = (const float*)d_in[3];
  const float* Wk = (const float*)d_in[4];
  const float* bk = (const float*)d_in[5];
  const float* Wv = (const float*)d_in[6];
  const float* bv = (const float*)d_in[7];
  const float* Wo = (const float*)d_in[8];
  const float* bo = (const float*)d_in[9];

  char* ws = (char*)d_ws;
  __hip_bfloat16* Xb   = (__hip_bfloat16*)(ws);                 // 32 MB
  __hip_bfloat16* Wqb  = (__hip_bfloat16*)(ws + 33554432);      // 8 MB
  __hip_bfloat16* Wkb  = (__hip_bfloat16*)(ws + 41943040);      // 8 MB
  __hip_bfloat16* Wvb  = (__hip_bfloat16*)(ws + 50331648);      // 8 MB
  __hip_bfloat16* Wob  = (__hip_bfloat16*)(ws + 58720256);      // 8 MB
  __hip_bfloat16* Qb   = (__hip_bfloat16*)(ws + 67108864);      // 32 MB
  __hip_bfloat16* Kb   = (__hip_bfloat16*)(ws + 100663296);     // 32 MB
  __hip_bfloat16* Ob   = (__hip_bfloat16*)(ws + 134217728);     // 32 MB (attn out)
  __hip_bfloat16* Vtb  = (__hip_bfloat16*)(ws + 167772160);     // 32 MB -> total 192 MB

  cvt5_kernel<<<dim3(512, 5), 256, 0, stream>>>(
      X, Wq, Wk, Wv, Wo,
      (unsigned short*)Xb,
      (unsigned short*)Wqb, (unsigned short*)Wkb,
      (unsigned short*)Wvb, (unsigned short*)Wob,
      16777216 / 4, 4194304 / 4);

  // Q projection pre-scaled by log2e/sqrt(d); V projection writes Vt directly.
  gemm8<0><<<256, 512, 0, stream>>>(Xb, Wqb, bq, Qb,  8192, 2048, 2048, SL2E);
  gemm8<0><<<256, 512, 0, stream>>>(Xb, Wkb, bk, Kb,  8192, 2048, 2048, 1.0f);
  gemm8<2><<<256, 512, 0, stream>>>(Xb, Wvb, bv, Vtb, 8192, 2048, 2048, 1.0f);

  attn_kernel<<<dim3(64, 12), 256, 0, stream>>>(Qb, Kb, Vtb, Ob);

  gemm8<1><<<256, 512, 0, stream>>>(Ob, Wob, bo, (float*)d_out, 8192, 2048, 2048, 1.0f);
}

// Round 12
// 433.255 us; speedup vs baseline: 1.0456x; 1.0456x over previous
//
#include <hip/hip_runtime.h>
#include <hip/hip_bf16.h>
#include <stdint.h>

#define S_LEN 2048
#define HDIM  2048
#define NH    16
#define HD    128
#define BATCH 4

typedef __attribute__((ext_vector_type(8))) short bf16x8;
typedef __attribute__((ext_vector_type(4))) float f32x4;
typedef __attribute__((ext_vector_type(4))) float float4v;
typedef __attribute__((ext_vector_type(4))) unsigned short u16x4;

__device__ __forceinline__ void gload_lds16(const void* g, void* l) {
  __builtin_amdgcn_global_load_lds(
      (const __attribute__((address_space(1))) unsigned int*)g,
      (__attribute__((address_space(3))) unsigned int*)l,
      16, 0, 0);
}

__device__ __forceinline__ unsigned short f2bf(float x) {
  __hip_bfloat16 b = __float2bfloat16(x);
  return *reinterpret_cast<unsigned short*>(&b);
}

#define SL2E 0.1275174465f   // (1/sqrt(128)) * log2(e) — folded into Q projection

// ---------------- fp32 -> bf16 convert: X + 4 weights in ONE launch ----------------
__global__ __launch_bounds__(256) void cvt5_kernel(
    const float* __restrict__ x,
    const float* __restrict__ w0, const float* __restrict__ w1,
    const float* __restrict__ w2, const float* __restrict__ w3,
    unsigned short* __restrict__ ox,
    unsigned short* __restrict__ o0, unsigned short* __restrict__ o1,
    unsigned short* __restrict__ o2, unsigned short* __restrict__ o3,
    int n4x, int n4w) {
  const int y = blockIdx.y;
  const float* in = (y == 0) ? x : (y == 1) ? w0 : (y == 2) ? w1 : (y == 3) ? w2 : w3;
  unsigned short* out = (y == 0) ? ox : (y == 1) ? o0 : (y == 2) ? o1 : (y == 3) ? o2 : o3;
  const int n4 = (y == 0) ? n4x : n4w;
  int stride = gridDim.x * blockDim.x;
  for (int i = blockIdx.x * blockDim.x + threadIdx.x; i < n4; i += stride) {
    float4v v = *(const float4v*)(in + (size_t)i * 4);
    u16x4 o;
    o.x = f2bf(v.x); o.y = f2bf(v.y); o.z = f2bf(v.z); o.w = f2bf(v.w);
    *(u16x4*)(out + (size_t)i * 4) = o;
  }
}

// ============ GEMM 256x256 8-phase (T2+T3+T4+T5) ============
// 512 thr = 8 waves (2M x 4N), per-wave 128x64 out, BK=64, 2 K-tiles/iter.
// LDS 128KB: buf0 {A 32K | B 32K} buf1 {A 32K | B 32K}; tiles [256 rows][64 k],
// 16B-chunk swizzle c ^= row&7 (inverse-swizzled global src + swizzled ds_read).
// gload source offset uses the FULL 64-lane index (HW writes dest+lane*16):
// row = lane>>3, chunk = (lane&7)^(lane>>3)  [r7 bug: used lane&15 -> absmax 4.28].
// Sync skeleton = verified m201 template: per phase
//   {ds_reads | stage 1 half} bar ; lgkmcnt(0) ; MFMA ; bar
// Stage map: ph0:A0(v) ph1:A1(v) ph2:B0(u+2) ph3:B1(u+2)+vmcnt(4)
//            ph4:A0(u+2) ph5:A1(u+2) ph6:B0(v+2) ph7:B1(v+2)+vmcnt(4)
// Epilogue stages clamp the K-tile index; vmcnt(0) drains before exit.

#define G8_VMW(N) asm volatile("s_waitcnt vmcnt(" #N ")" ::: "memory")
#define G8_BAR1() do { __builtin_amdgcn_sched_barrier(0); __builtin_amdgcn_s_barrier(); \
  asm volatile("s_waitcnt lgkmcnt(0)" ::: "memory"); __builtin_amdgcn_sched_barrier(0); } while (0)
#define G8_BAR2() do { __builtin_amdgcn_sched_barrier(0); __builtin_amdgcn_s_barrier(); \
  __builtin_amdgcn_sched_barrier(0); } while (0)

#define G8_STAGE(ISB, BUF, HALF, KT) do {                                          \
  int kt_ = (KT); if (kt_ > nkt1) kt_ = nkt1;                                      \
  const char* gs_ = ((ISB) ? Bg : Ag) +                                            \
      (size_t)(((ISB) ? bn : bm) * 256 + (HALF) * 128 + w * 16) * (size_t)K2 +     \
      (size_t)kt_ * 128;                                                           \
  char* ld_ = lds + (BUF) * 65536 + (ISB) * 32768 + ((HALF) * 128 + w * 16) * 128; \
  gload_lds16(gs_ + sLn, ld_);                                                     \
  gload_lds16(gs_ + 8 * (size_t)K2 + sLn, ld_ + 1024);                             \
} while (0)

#define G8_RDA(BUF, MI0) do {                                                      \
  _Pragma("unroll") for (int mi = 0; mi < 4; ++mi)                                 \
  _Pragma("unroll") for (int kk = 0; kk < 2; ++kk)                                 \
    a[mi][kk] = *(const bf16x8*)(lds + (BUF) * 65536 +                             \
        (wm + ((MI0) + mi) * 16 + ln) * 128 + ((((kk << 2) + g) ^ ln7) << 4));     \
} while (0)

#define G8_RDB(BUF, NI0, BREG) do {                                                \
  _Pragma("unroll") for (int ni = 0; ni < 2; ++ni)                                 \
  _Pragma("unroll") for (int kk = 0; kk < 2; ++kk)                                 \
    BREG[ni][kk] = *(const bf16x8*)(lds + (BUF) * 65536 + 32768 +                  \
        (wn + ((NI0) + ni) * 16 + ln) * 128 + ((((kk << 2) + g) ^ ln7) << 4));     \
} while (0)

#define G8_MFMA(M0, N0, BREG) do {                                                 \
  __builtin_amdgcn_s_setprio(1);                                                   \
  _Pragma("unroll") for (int mi = 0; mi < 4; ++mi)                                 \
  _Pragma("unroll") for (int ni = 0; ni < 2; ++ni)                                 \
  _Pragma("unroll") for (int kk = 0; kk < 2; ++kk)                                 \
    acc[(M0) + mi][(N0) + ni] = __builtin_amdgcn_mfma_f32_16x16x32_bf16(           \
        a[mi][kk], BREG[ni][kk], acc[(M0) + mi][(N0) + ni], 0, 0, 0);              \
  __builtin_amdgcn_s_setprio(0);                                                   \
} while (0)

// Shared main loop body (prologue + K loop), expects locals:
// lds, w, lane, g, ln, ln7, K2, nkt1, niter, bm, bn, wm, wn, Ag, Bg, sLn, acc.
#define G8_MAIN_LOOP() do {                                                        \
  G8_STAGE(0, 0, 0, 0); G8_STAGE(0, 0, 1, 0);                                      \
  G8_STAGE(1, 0, 0, 0); G8_STAGE(1, 0, 1, 0);                                      \
  G8_STAGE(1, 1, 0, 1); G8_STAGE(1, 1, 1, 1);                                      \
  G8_VMW(4);                                                                       \
  G8_BAR2();                                                                       \
  for (int i = 0; i < niter; ++i) {                                                \
    const int v = 2 * i + 1, u2 = 2 * i + 2, v2 = 2 * i + 3;                       \
    bf16x8 a[4][2], b0[2][2], b1[2][2];                                            \
    G8_RDA(0, 0); G8_RDB(0, 0, b0);                                                \
    G8_STAGE(0, 1, 0, v);                                                          \
    G8_BAR1(); G8_MFMA(0, 0, b0); G8_BAR2();                                       \
    G8_RDB(0, 2, b1);                                                              \
    G8_STAGE(0, 1, 1, v);                                                          \
    G8_BAR1(); G8_MFMA(0, 2, b1); G8_BAR2();                                       \
    G8_RDA(0, 4);                                                                  \
    G8_STAGE(1, 0, 0, u2);                                                         \
    G8_BAR1(); G8_MFMA(4, 0, b0); G8_BAR2();                                       \
    G8_STAGE(1, 0, 1, u2);                                                         \
    G8_VMW(4);                                                                     \
    G8_BAR1(); G8_MFMA(4, 2, b1); G8_BAR2();                                       \
    G8_RDA(1, 0); G8_RDB(1, 0, b0);                                                \
    G8_STAGE(0, 0, 0, u2);                                                         \
    G8_BAR1(); G8_MFMA(0, 0, b0); G8_BAR2();                                       \
    G8_RDB(1, 2, b1);                                                              \
    G8_STAGE(0, 0, 1, u2);                                                         \
    G8_BAR1(); G8_MFMA(0, 2, b1); G8_BAR2();                                       \
    G8_RDA(1, 4);                                                                  \
    G8_STAGE(1, 1, 0, v2);                                                         \
    G8_BAR1(); G8_MFMA(4, 0, b0); G8_BAR2();                                       \
    G8_STAGE(1, 1, 1, v2);                                                         \
    G8_VMW(4);                                                                     \
    G8_BAR1(); G8_MFMA(4, 2, b1); G8_BAR2();                                       \
  }                                                                                \
  G8_VMW(0);                                                                       \
} while (0)

// ---- merged Q/K/V projection: blocks 0-255 -> Q (scaled), 256-511 -> K,
// ---- 512-767 -> V (scattered to Vt). Same inner loop; one dispatch removes
// ---- two inter-GEMM ramp/tail gaps.
__global__ __launch_bounds__(512, 2) void gemm8_qkv(
    const __hip_bfloat16* __restrict__ A,
    const __hip_bfloat16* __restrict__ Bq, const __hip_bfloat16* __restrict__ Bk,
    const __hip_bfloat16* __restrict__ Bv,
    const float* __restrict__ biasq, const float* __restrict__ biask,
    const float* __restrict__ biasv,
    __hip_bfloat16* __restrict__ Cq, __hip_bfloat16* __restrict__ Ck,
    __hip_bfloat16* __restrict__ Cv,
    int M, int N, int K) {
  __shared__ char lds[131072];
  const int tid = threadIdx.x;
  const int w = tid >> 6;
  const int lane = tid & 63;
  const int g = lane >> 4;
  const int ln = lane & 15;
  const int ln7 = lane & 7;
  const int K2 = K * 2;
  const int nkt = K >> 6;
  const int nkt1 = nkt - 1;
  const int niter = nkt >> 1;

  const int proj = blockIdx.x >> 8;      // 0=Q 1=K 2=V
  const int bid  = blockIdx.x & 255;
  // XCD-chunked bijective swizzle within each 256-block projection group
  // (group offset is a multiple of 8 so XCD = blockIdx.x % 8 is preserved).
  const int NBN = N >> 8;                // 8
  const int cpx = ((M >> 8) * NBN) >> 3; // 32
  const int wg = (bid & 7) * cpx + (bid >> 3);
  const int bm = wg / NBN, bn = wg % NBN;

  const int wm = (w >> 2) * 128;
  const int wn = (w & 3) * 64;

  const char* Ag = (const char*)A;
  const char* Bg = (proj == 0) ? (const char*)Bq : (proj == 1) ? (const char*)Bk
                                                               : (const char*)Bv;
  const float* bias = (proj == 0) ? biasq : (proj == 1) ? biask : biasv;
  const float scale = (proj == 0) ? SL2E : 1.0f;
  const size_t sLn = (size_t)(lane >> 3) * (size_t)K2 +
                     (size_t)(((lane & 7) ^ (lane >> 3)) << 4);

  f32x4 acc[8][4];
#pragma unroll
  for (int mi = 0; mi < 8; ++mi)
#pragma unroll
    for (int ni = 0; ni < 4; ++ni) acc[mi][ni] = (f32x4){0.f, 0.f, 0.f, 0.f};

  G8_MAIN_LOOP();

#pragma unroll
  for (int ni = 0; ni < 4; ++ni) {
    const int col = bn * 256 + wn + ni * 16 + ln;
    const float bv = bias[col];
#pragma unroll
    for (int mi = 0; mi < 8; ++mi) {
      const int row0 = bm * 256 + wm + mi * 16 + g * 4;
      if (proj == 2) {
        // Vt[((b*NH+h)*HD + d)*S_LEN + s], col = h*HD+d, 4 consecutive s/lane
        const int h = col >> 7, d = col & 127;
        const size_t base = ((size_t)((row0 >> 11) * NH + h) * HD + d) * S_LEN +
                            (row0 & (S_LEN - 1));
        u16x4 pk;
#pragma unroll
        for (int r = 0; r < 4; ++r) pk[r] = f2bf(acc[mi][ni][r] + bv);
        *(u16x4*)((unsigned short*)Cv + base) = pk;
      } else {
        __hip_bfloat16* C = (proj == 0) ? Cq : Ck;
#pragma unroll
        for (int r = 0; r < 4; ++r)
          C[(size_t)(row0 + r) * N + col] = __float2bfloat16((acc[mi][ni][r] + bv) * scale);
      }
    }
  }
}

// ---- O projection: f32 row-major out (unchanged template, single instantiation)
template<int OUTMODE>
__global__ __launch_bounds__(512, 2) void gemm8(
    const __hip_bfloat16* __restrict__ A, const __hip_bfloat16* __restrict__ B,
    const float* __restrict__ bias, void* __restrict__ C,
    int M, int N, int K, float scale) {
  __shared__ char lds[131072];
  const int tid = threadIdx.x;
  const int w = tid >> 6;
  const int lane = tid & 63;
  const int g = lane >> 4;
  const int ln = lane & 15;
  const int ln7 = lane & 7;
  const int K2 = K * 2;
  const int nkt = K >> 6;
  const int nkt1 = nkt - 1;
  const int niter = nkt >> 1;

  const int NBN = N >> 8;
  const int nwg = (M >> 8) * NBN;
  const int cpx = nwg >> 3;
  const int bid = blockIdx.x;
  const int wg = (bid & 7) * cpx + (bid >> 3);
  const int bm = wg / NBN, bn = wg % NBN;

  const int wm = (w >> 2) * 128;
  const int wn = (w & 3) * 64;

  const char* Ag = (const char*)A;
  const char* Bg = (const char*)B;
  const size_t sLn = (size_t)(lane >> 3) * (size_t)K2 +
                     (size_t)(((lane & 7) ^ (lane >> 3)) << 4);

  f32x4 acc[8][4];
#pragma unroll
  for (int mi = 0; mi < 8; ++mi)
#pragma unroll
    for (int ni = 0; ni < 4; ++ni) acc[mi][ni] = (f32x4){0.f, 0.f, 0.f, 0.f};

  G8_MAIN_LOOP();

#pragma unroll
  for (int ni = 0; ni < 4; ++ni) {
    const int col = bn * 256 + wn + ni * 16 + ln;
    const float bv = bias[col];
#pragma unroll
    for (int mi = 0; mi < 8; ++mi) {
      const int row0 = bm * 256 + wm + mi * 16 + g * 4;
#pragma unroll
      for (int r = 0; r < 4; ++r) {
        float val = (acc[mi][ni][r] + bv) * scale;
        if (OUTMODE == 1)
          ((float*)C)[(size_t)(row0 + r) * N + col] = val;
        else
          ((__hip_bfloat16*)C)[(size_t)(row0 + r) * N + col] = __float2bfloat16(val);
      }
    }
  }
}

// ---------------- causal flash attention (r10 version — 48 KB, 2 blocks/CU) ----
// r11 LESSON: halving q-rows/wave for (256,3) occupancy regressed 170->193 µs
// (per-tile staging/barrier overhead doubled while MFMA per tile halved;
// MfmaUtil 17.7->15.7, bank-conflicts 2x). Occupancy bought by shrinking the
// work quantum loses when per-quantum overhead is fixed. Reverted to r10.
// Grid (64, 8): bh = blockIdx.x so the 8 blocks sharing one (b,h)'s K/V have
// bids == bh (mod 8) -> SAME XCD -> K/V re-reads are L2 hits (FETCH 302->86MB).
// Pair-balanced: pass 0 qt = 15-p, pass 1 qt = p (uniform 34 tile-units).
// Q is PRE-SCALED by log2e/sqrt(d) in its projection (log2-domain scores).
// LDS map: K [0,16K) | V [16K,32K) | P [32K,48K); swizzle per rule #21.
// launch_bounds(256,2): (256,3) caps regs at 170 < ~188 needed -> spill (r3/r4).
#define DEFER_THR 8.0f       // T13 (log2 domain): P bounded by 2^8

__global__ __launch_bounds__(256, 2) void attn_kernel(
    const __hip_bfloat16* __restrict__ Q, const __hip_bfloat16* __restrict__ Kg,
    const __hip_bfloat16* __restrict__ Vt, __hip_bfloat16* __restrict__ O) {
  __shared__ char lds[49152];
  const int tid = threadIdx.x;
  const int w = tid >> 6;
  const int lane = tid & 63;
  const int g = lane >> 4;
  const int ln = lane & 15;
  const int bh = blockIdx.x;            // XCD-aligned: bid%8 == bh%8
  const int pairid = blockIdx.y;        // 0..7
  const int b = bh >> 4, h = bh & 15;

  const char* Qb = (const char*)Q + ((size_t)b * S_LEN * HDIM + h * HD) * 2;
  const char* Kb = (const char*)Kg + ((size_t)b * S_LEN * HDIM + h * HD) * 2;
  const char* Vb = (const char*)Vt + ((size_t)bh * HD * S_LEN) * 2;
  char* ldsK = lds;
  char* ldsV = lds + 16384;
  char* pw   = lds + 32768 + w * 4096;

  const int kr = lane >> 4;   // K: row within 4-row group
  const int kc = lane & 15;   // K: 16B chunk 0..15
  const int vr = lane >> 3;   // V: row within 8-row group (== row&7)
  const int vc = lane & 7;    // V: 16B chunk 0..7

  auto stage = [&](int kv0) {
#pragma unroll
    for (int i = 0; i < 4; i++) {
      int r = w * 16 + i * 4 + kr;  // K row 0..63
      gload_lds16(Kb + (size_t)(kv0 + r) * (HDIM * 2) + ((kc ^ (r & 7)) << 4),
                  ldsK + (w * 16 + i * 4) * 256);
    }
#pragma unroll
    for (int i = 0; i < 4; i++) {
      int r = w * 32 + i * 8 + vr;  // V row (d) 0..127; r&7 == vr
      gload_lds16(Vb + (size_t)r * (S_LEN * 2) + (size_t)kv0 * 2 + ((vc ^ vr) << 4),
                  ldsV + (w * 32 + i * 8) * 128);
    }
  };

  for (int pass = 0; pass < 2; pass++) {
    const int qt = pass == 0 ? (15 - pairid) : pairid;
    const int q0 = qt * 128 + w * 32;  // this wave's first q row

    const int nt = 2 * qt + 2;  // block-uniform kv tile count (causal)
    __syncthreads();            // protect prior pass's last-tile LDS reads
    stage(0);                   // issue tile-0 staging first...

    // ...then overlap Q-fragment loads with the staging gloads
    bf16x8 qf[2][4];
#pragma unroll
    for (int qs = 0; qs < 2; qs++)
#pragma unroll
      for (int dc = 0; dc < 4; dc++)
        qf[qs][dc] = *(const bf16x8*)(Qb + (size_t)(q0 + qs * 16 + ln) * HDIM * 2 +
                                      (dc * 32 + g * 8) * 2);

    f32x4 o[2][8];
#pragma unroll
    for (int qs = 0; qs < 2; qs++)
#pragma unroll
      for (int ds = 0; ds < 8; ds++) o[qs][ds] = (f32x4){0.f, 0.f, 0.f, 0.f};
    float mrun[2][4], lrun[2][4];
#pragma unroll
    for (int qs = 0; qs < 2; qs++)
#pragma unroll
      for (int r = 0; r < 4; r++) { mrun[qs][r] = -__builtin_inff(); lrun[qs][r] = 0.f; }

    __syncthreads();

    for (int t = 0; t < nt; t++) {
      const int kv0 = t * 64;

      if (kv0 <= q0 + 31) {  // wave-uniform: skip fully-masked tiles
        f32x4 sa[2][4];
#pragma unroll
        for (int qs = 0; qs < 2; qs++)
#pragma unroll
          for (int ks = 0; ks < 4; ks++) sa[qs][ks] = (f32x4){0.f, 0.f, 0.f, 0.f};
#pragma unroll
        for (int dc = 0; dc < 4; dc++) {
          bf16x8 kf[4];
#pragma unroll
          for (int ks = 0; ks < 4; ks++)
            kf[ks] = *(const bf16x8*)(ldsK + (ks * 16 + ln) * 256 +
                                      (((dc * 4 + g) ^ (ln & 7)) << 4));
          __builtin_amdgcn_s_setprio(1);   // T5: favor MFMA burst
#pragma unroll
          for (int qs = 0; qs < 2; qs++)
#pragma unroll
            for (int ks = 0; ks < 4; ks++)
              sa[qs][ks] = __builtin_amdgcn_mfma_f32_16x16x32_bf16(qf[qs][dc], kf[ks], sa[qs][ks], 0, 0, 0);
          __builtin_amdgcn_s_setprio(0);
        }
        // scores already log2-domain (Q pre-scaled); apply causal mask only
        const bool needmask = (kv0 + 63) > q0;
        if (needmask) {
#pragma unroll
          for (int qs = 0; qs < 2; qs++)
#pragma unroll
            for (int ks = 0; ks < 4; ks++)
#pragma unroll
              for (int r = 0; r < 4; r++)
                if ((kv0 + ks * 16 + ln) > (q0 + qs * 16 + g * 4 + r))
                  sa[qs][ks][r] = -__builtin_inff();
        }
        float pmax[2][4];
#pragma unroll
        for (int qs = 0; qs < 2; qs++)
#pragma unroll
          for (int r = 0; r < 4; r++) {
            float mx = fmaxf(fmaxf(sa[qs][0][r], sa[qs][1][r]), fmaxf(sa[qs][2][r], sa[qs][3][r]));
            mx = fmaxf(mx, __shfl_xor(mx, 1));
            mx = fmaxf(mx, __shfl_xor(mx, 2));
            mx = fmaxf(mx, __shfl_xor(mx, 4));
            mx = fmaxf(mx, __shfl_xor(mx, 8));
            pmax[qs][r] = mx;
          }
        float dmin = 1e30f;
#pragma unroll
        for (int qs = 0; qs < 2; qs++)
#pragma unroll
          for (int r = 0; r < 4; r++)
            dmin = fminf(dmin, mrun[qs][r] + DEFER_THR - pmax[qs][r]);
        if (!__all(dmin >= 0.0f)) {
          float alpha[2][4];
#pragma unroll
          for (int qs = 0; qs < 2; qs++)
#pragma unroll
            for (int r = 0; r < 4; r++) {
              float mn = fmaxf(mrun[qs][r], pmax[qs][r]);
              alpha[qs][r] = exp2f(mrun[qs][r] - mn);
              mrun[qs][r] = mn;
              lrun[qs][r] *= alpha[qs][r];
            }
#pragma unroll
          for (int qs = 0; qs < 2; qs++)
#pragma unroll
            for (int ds = 0; ds < 8; ds++)
#pragma unroll
              for (int r = 0; r < 4; r++) o[qs][ds][r] *= alpha[qs][r];
        }
        float rsum[2][4];
#pragma unroll
        for (int qs = 0; qs < 2; qs++)
#pragma unroll
          for (int r = 0; r < 4; r++) rsum[qs][r] = 0.f;
#pragma unroll
        for (int qs = 0; qs < 2; qs++)
#pragma unroll
          for (int ks = 0; ks < 4; ks++)
#pragma unroll
            for (int r = 0; r < 4; r++) {
              float p = exp2f(sa[qs][ks][r] - mrun[qs][r]);
              sa[qs][ks][r] = p;
              rsum[qs][r] += p;
            }
#pragma unroll
        for (int qs = 0; qs < 2; qs++)
#pragma unroll
          for (int r = 0; r < 4; r++) {
            float rs = rsum[qs][r];
            rs += __shfl_xor(rs, 1);
            rs += __shfl_xor(rs, 2);
            rs += __shfl_xor(rs, 4);
            rs += __shfl_xor(rs, 8);
            lrun[qs][r] += rs;
          }
#pragma unroll
        for (int qs = 0; qs < 2; qs++)
#pragma unroll
          for (int ks = 0; ks < 4; ks++)
#pragma unroll
            for (int r = 0; r < 4; r++) {
              int row = qs * 16 + g * 4 + r;
              int key = ks * 16 + ln;
              *(__hip_bfloat16*)(pw + row * 128 + (((key >> 3) ^ (row & 7)) << 4) + (key & 7) * 2) =
                  __float2bfloat16(sa[qs][ks][r]);
            }
#pragma unroll
        for (int kk = 0; kk < 2; kk++) {
          bf16x8 pa[2];
#pragma unroll
          for (int qs = 0; qs < 2; qs++) {
            int row = qs * 16 + ln;
            pa[qs] = *(const bf16x8*)(pw + row * 128 + (((kk * 4 + g) ^ (row & 7)) << 4));
          }
          __builtin_amdgcn_s_setprio(1);   // T5
#pragma unroll
          for (int ds = 0; ds < 8; ds++) {
            bf16x8 vf = *(const bf16x8*)(ldsV + (ds * 16 + ln) * 128 +
                                         (((kk * 4 + g) ^ (ln & 7)) << 4));
#pragma unroll
            for (int qs = 0; qs < 2; qs++)
              o[qs][ds] = __builtin_amdgcn_mfma_f32_16x16x32_bf16(pa[qs], vf, o[qs][ds], 0, 0, 0);
          }
          __builtin_amdgcn_s_setprio(0);
        }
      }

      if (t + 1 < nt) {
        __syncthreads();
        stage(kv0 + 64);
        __syncthreads();
      }
    }
    float inv[2][4];
#pragma unroll
    for (int qs = 0; qs < 2; qs++)
#pragma unroll
      for (int r = 0; r < 4; r++) inv[qs][r] = 1.0f / lrun[qs][r];
    __hip_bfloat16* Ob = O + (size_t)b * S_LEN * HDIM + h * HD;
#pragma unroll
    for (int qs = 0; qs < 2; qs++)
#pragma unroll
      for (int ds = 0; ds < 8; ds++)
#pragma unroll
        for (int r = 0; r < 4; r++)
          Ob[(size_t)(q0 + qs * 16 + g * 4 + r) * HDIM + ds * 16 + ln] =
              __float2bfloat16(o[qs][ds][r] * inv[qs][r]);
  }
}

extern "C" void kernel_launch(void* const* d_in, const int* in_sizes, int n_in,
                              void* d_out, int out_size, void* d_ws, size_t ws_size,
                              hipStream_t stream) {
  const float* X  = (const float*)d_in[0];
  const float* Wq = (const float*)d_in[2];
  const float* bq = (const float*)d_in[3];
  const float* Wk = (const float*)d_in[4];
  const float* bk = (const float*)d_in[5];
  const float* Wv = (const float*)d_in[6];
  const float* bv = (const float*)d_in[7];
  const float* Wo = (const float*)d_in[8];
  const float* bo = (const float*)d_in[9];

  char* ws = (char*)d_ws;
  __hip_bfloat16* Xb   = (__hip_bfloat16*)(ws);                 // 32 MB
  __hip_bfloat16* Wqb  = (__hip_bfloat16*)(ws + 33554432);      // 8 MB
  __hip_bfloat16* Wkb  = (__hip_bfloat16*)(ws + 41943040);      // 8 MB
  __hip_bfloat16* Wvb  = (__hip_bfloat16*)(ws + 50331648);      // 8 MB
  __hip_bfloat16* Wob  = (__hip_bfloat16*)(ws + 58720256);      // 8 MB
  __hip_bfloat16* Qb   = (__hip_bfloat16*)(ws + 67108864);      // 32 MB
  __hip_bfloat16* Kb   = (__hip_bfloat16*)(ws + 100663296);     // 32 MB
  __hip_bfloat16* Ob   = (__hip_bfloat16*)(ws + 134217728);     // 32 MB (attn out)
  __hip_bfloat16* Vtb  = (__hip_bfloat16*)(ws + 167772160);     // 32 MB -> total 192 MB

  cvt5_kernel<<<dim3(512, 5), 256, 0, stream>>>(
      X, Wq, Wk, Wv, Wo,
      (unsigned short*)Xb,
      (unsigned short*)Wqb, (unsigned short*)Wkb,
      (unsigned short*)Wvb, (unsigned short*)Wob,
      16777216 / 4, 4194304 / 4);

  // Merged QKV projections (Q pre-scaled by log2e/sqrt(d), V scattered to Vt).
  gemm8_qkv<<<768, 512, 0, stream>>>(Xb, Wqb, Wkb, Wvb, bq, bk, bv,
                                     Qb, Kb, Vtb, 8192, 2048, 2048);

  attn_kernel<<<dim3(64, 8), 256, 0, stream>>>(Qb, Kb, Vtb, Ob);

  gemm8<1><<<256, 512, 0, stream>>>(Ob, Wob, bo, (float*)d_out, 8192, 2048, 2048, 1.0f);
}